// Round 7
// baseline (253.502 us; speedup 1.0000x reference)
//
#include <hip/hip_runtime.h>
#include <math.h>

// EnergySRB, R7: R4 skeleton (fastest: 79.5us) + EARLY DISTANCE REJECT.
// Theory: the wall is the per-CU LDS pipe under divergent addressing
// (~25-50 cyc per random-address wave64 ds op; 2 gathers + tab + atomic
// ~= 125 cyc per 64-pair group x 1024 groups ~= the ~190K-cycle wall).
// Masked-out lanes consume no LDS bank passes, so predicate EVERYTHING:
//   db >= 7.9 bohr  =>  q = trunc(|pre|*exp(arg)*2^27) = 0 for ALL species
//   (|pre| <= 0.064, dfac <= -2, cut(7.9) = -1.83 -> mag <= 1.4e-9 < 2^-27,
//    5x margin) -- covers ~32% of pairs; skip gathers+tab+exp+atomic.
// The old (db < rc) cndmask is subsumed (7.9 < rc = 9.83) and dropped.

#define NT        1024
#define NBLK      256
#define SCALE_F   134217728.0f              // 2^27
#define INV_SCALE 7.450580596923828125e-9   // 2^-27, exact in double
#define DB_REJECT 7.9f                      // bohr; q==0 proven beyond this

// ---------------------------------------------------------------------------
// pack species (values 0..3) into 2-bit words. 262144 atoms -> 64KB.
__global__ void pack_species_kernel(const int* __restrict__ sp,
                                    unsigned* __restrict__ packed, int nwords) {
    int w = blockIdx.x * blockDim.x + threadIdx.x;
    if (w >= nwords) return;
    const int4* p4 = (const int4*)(sp + (w << 4));
    int4 a = p4[0], b = p4[1], c = p4[2], d = p4[3];
    unsigned v =
        (unsigned)(a.x & 3)        | ((unsigned)(a.y & 3) << 2)  |
        ((unsigned)(a.z & 3) << 4) | ((unsigned)(a.w & 3) << 6)  |
        ((unsigned)(b.x & 3) << 8) | ((unsigned)(b.y & 3) << 10) |
        ((unsigned)(b.z & 3) << 12)| ((unsigned)(b.w & 3) << 14) |
        ((unsigned)(c.x & 3) << 16)| ((unsigned)(c.y & 3) << 18) |
        ((unsigned)(c.z & 3) << 20)| ((unsigned)(c.w & 3) << 22) |
        ((unsigned)(d.x & 3) << 24)| ((unsigned)(d.y & 3) << 26) |
        ((unsigned)(d.z & 3) << 28)| ((unsigned)(d.w & 3) << 30);
    packed[w] = v;
}

// ---------------------------------------------------------------------------
// init: species passthrough to out[0:n_species); zero the u64 accumulator.
__global__ void init_kernel(const int* __restrict__ species,
                            float* __restrict__ out,
                            unsigned long long* __restrict__ acc,
                            int n_species, int n_mol) {
    int i = blockIdx.x * blockDim.x + threadIdx.x;
    if (i < n_species) out[i] = (float)species[i];
    if (i < n_mol)     acc[i] = 0ull;
}

// ---------------------------------------------------------------------------
// Fused main kernel (R4 structure + early reject).
__global__ __launch_bounds__(NT, 1)
void srb_fused_u32(const unsigned* __restrict__ packed_ws,
                   const int* __restrict__ ai,     // [2, P]
                   const float* __restrict__ dist, // [P] angstrom
                   const float* __restrict__ pre_tab,   // 16 floats (negative)
                   const float* __restrict__ dfac_tab,  // 16 floats
                   unsigned long long* __restrict__ acc, // [n_mol]
                   int P, int mol_shift) {
    __shared__ unsigned packed[16384]; // 64KB: 2-bit species, all atoms
    __shared__ unsigned binsu[4096];   // 16KB: fixed-point per-mol sums
    __shared__ float2 tabr[4][18];     // 4 padded copies: (|pre|, dfac)

    const int t = threadIdx.x;
    for (int i = t; i < 4096; i += NT) binsu[i] = 0u;
    if (t < 64) {
        int e = t & 15;
        tabr[t >> 4][e] = make_float2(-pre_tab[e], dfac_tab[e]); // magnitude
    }
    {
        int4* dst = (int4*)packed;
        const int4* src = (const int4*)packed_ws;
        for (int i = t; i < 4096; i += NT) dst[i] = src[i];
    }
    __syncthreads();

    const float a2b   = (float)1.8897261258369282;
    const float rcinv = (float)(1.0 / (5.2 * 1.8897261258369282));
    const int   copy  = t & 3;

    auto body = [&](int a0, int a1, float dang) {
        float db = dang * a2b;
        if (db < DB_REJECT) {   // ~68% of lanes; others: q==0 proven
            unsigned ua0 = (unsigned)a0, ua1 = (unsigned)a1;
            unsigned s0 = (packed[ua0 >> 4] >> ((ua0 & 15u) << 1)) & 3u;
            unsigned s1 = (packed[ua1 >> 4] >> ((ua1 & 15u) << 1)) & 3u;
            float2 td = tabr[copy][(s0 << 2) | s1];
            float x   = db * rcinv;
            float arg = td.y * db + (1.0f - 1.0f / (1.0f - x * x));
            float mag = td.x * __expf(arg);      // td.x = |pre| > 0
            unsigned q = (unsigned)(mag * SCALE_F); // trunc; < 2^21 always
            if (q) atomicAdd(&binsu[ua0 >> mol_shift], q); // native ds_add_u32
        }
    };

    const int nv     = P >> 2;
    const int stride = (int)gridDim.x * NT;
    const int4*   v0 = (const int4*)ai;
    const int4*   v1 = (const int4*)(ai + P);
    const float4* dv = (const float4*)dist;
    for (int v = (int)blockIdx.x * NT + t; v < nv; v += stride) {
        int4 i0 = v0[v]; int4 i1 = v1[v]; float4 dd = dv[v];
        body(i0.x, i1.x, dd.x); body(i0.y, i1.y, dd.y);
        body(i0.z, i1.z, dd.z); body(i0.w, i1.w, dd.w);
    }

    __syncthreads();
    for (int i = t; i < 4096; i += NT) {
        unsigned v = binsu[i];
        if (v) atomicAdd(&acc[i], (unsigned long long)v); // native u64 atomic
    }
}

// ---------------------------------------------------------------------------
// final: out_e[m] = energies[m] - acc[m] * 2^-27  (exact in double)
__global__ void final_kernel(const unsigned long long* __restrict__ acc,
                             const float* __restrict__ energies,
                             float* __restrict__ out_e, int n_mol) {
    int m = blockIdx.x * blockDim.x + threadIdx.x;
    if (m < n_mol)
        out_e[m] = energies[m] - (float)((double)acc[m] * INV_SCALE);
}

// ---------------------------------------------------------------------------
// Fallback main kernel (P not multiple of 4): scalar loop, same math.
__global__ __launch_bounds__(NT, 1)
void srb_fused_scalar(const unsigned* __restrict__ packed_ws,
                      const int* __restrict__ ai,
                      const float* __restrict__ dist,
                      const float* __restrict__ pre_tab,
                      const float* __restrict__ dfac_tab,
                      unsigned long long* __restrict__ acc,
                      int P, int mol_shift) {
    __shared__ unsigned packed[16384];
    __shared__ unsigned binsu[4096];
    __shared__ float2 tabr[4][18];
    const int t = threadIdx.x;
    for (int i = t; i < 4096; i += NT) binsu[i] = 0u;
    if (t < 64) {
        int e = t & 15;
        tabr[t >> 4][e] = make_float2(-pre_tab[e], dfac_tab[e]);
    }
    {
        int4* dst = (int4*)packed;
        const int4* src = (const int4*)packed_ws;
        for (int i = t; i < 4096; i += NT) dst[i] = src[i];
    }
    __syncthreads();
    const float a2b   = (float)1.8897261258369282;
    const float rcinv = (float)(1.0 / (5.2 * 1.8897261258369282));
    const int   copy  = t & 3;
    const int stride = (int)gridDim.x * NT;
    for (int p = (int)blockIdx.x * NT + t; p < P; p += stride) {
        unsigned ua0 = (unsigned)ai[p], ua1 = (unsigned)ai[P + p];
        float db = dist[p] * a2b;
        if (db < DB_REJECT) {
            unsigned s0 = (packed[ua0 >> 4] >> ((ua0 & 15u) << 1)) & 3u;
            unsigned s1 = (packed[ua1 >> 4] >> ((ua1 & 15u) << 1)) & 3u;
            float2 td = tabr[copy][(s0 << 2) | s1];
            float x   = db * rcinv;
            float arg = td.y * db + (1.0f - 1.0f / (1.0f - x * x));
            float mag = td.x * __expf(arg);
            unsigned q = (unsigned)(mag * SCALE_F);
            if (q) atomicAdd(&binsu[ua0 >> mol_shift], q);
        }
    }
    __syncthreads();
    for (int i = t; i < 4096; i += NT) {
        unsigned v = binsu[i];
        if (v) atomicAdd(&acc[i], (unsigned long long)v);
    }
}

// ---------------------------------------------------------------------------
extern "C" void kernel_launch(void* const* d_in, const int* in_sizes, int n_in,
                              void* d_out, int out_size, void* d_ws, size_t ws_size,
                              hipStream_t stream) {
    const int*   species  = (const int*)d_in[0];
    const float* energies = (const float*)d_in[1];
    const int*   ai       = (const int*)d_in[2];
    const float* dist     = (const float*)d_in[3];
    const float* pre_tab  = (const float*)d_in[4];
    const float* dfac_tab = (const float*)d_in[5];

    const int n_species = in_sizes[0];            // 262144
    const int n_mol     = in_sizes[1];            // 4096
    const int P         = in_sizes[3];            // 16777216
    const int n_atoms   = n_species / n_mol;      // 64

    int mol_shift = 0;
    while ((1 << mol_shift) < n_atoms) ++mol_shift; // 6

    float* out   = (float*)d_out;
    float* out_e = out + n_species;

    const int    nwords    = n_species / 16;              // 16384
    const size_t packed_sz = (size_t)nwords * 4;          // 64KB

    unsigned*           packed = (unsigned*)d_ws;
    unsigned long long* acc    = (unsigned long long*)((char*)d_ws + packed_sz);

    init_kernel<<<(n_species + 255) / 256, 256, 0, stream>>>(
        species, out, acc, n_species, n_mol);
    pack_species_kernel<<<(nwords + 255) / 256, 256, 0, stream>>>(
        species, packed, nwords);

    if ((P & 3) == 0) {
        srb_fused_u32<<<NBLK, NT, 0, stream>>>(
            packed, ai, dist, pre_tab, dfac_tab, acc, P, mol_shift);
    } else {
        srb_fused_scalar<<<NBLK, NT, 0, stream>>>(
            packed, ai, dist, pre_tab, dfac_tab, acc, P, mol_shift);
    }
    final_kernel<<<(n_mol + 255) / 256, 256, 0, stream>>>(
        acc, energies, out_e, n_mol);
}

// Round 8
// 251.656 us; speedup vs baseline: 1.0073x; 1.0073x over previous
//
#include <hip/hip_runtime.h>
#include <math.h>

// EnergySRB, FINAL (revert to R4 = best measured: main 79.5us, total 250.6-251.5us).
// Design: fused pair kernel.
//  - species (0..3) packed 2-bit into a 64KB LDS table -> random per-pair
//    species gathers stay on-chip (ds_read).
//  - segment_sum via NATIVE u32 LDS atomics (ds_add_u32) on fixed-point
//    magnitudes: srb is strictly negative, |srb| <= 0.0097; accumulate
//    q = trunc(|srb| * 2^27) per molecule (overflow margin >100x; quantization
//    ~1e-5 << 6e-2 threshold). This replaced float LDS atomicAdd (CAS-loop
//    lowering) and was the single biggest win of the session (96.5 -> 79.5us).
//  - per-block flush via native u64 global atomics into ws acc[4096];
//    final kernel: out_e[m] = energies[m] - acc[m]*2^-27 (exact in double).
// Falsified alternatives (kept out deliberately): kernel split (R3, adds a
// full extra stream pass), source-level ILP batching (R2/R5, compiler
// re-serializes; VGPR pinned at 52), global_load_lds staging (R6, neutral),
// early-distance predication (R7, regressed).

#define NT        1024
#define NBLK      256
#define SCALE_F   134217728.0f              // 2^27
#define INV_SCALE 7.450580596923828125e-9   // 2^-27, exact in double

// ---------------------------------------------------------------------------
// pack species (values 0..3) into 2-bit words. 262144 atoms -> 64KB.
__global__ void pack_species_kernel(const int* __restrict__ sp,
                                    unsigned* __restrict__ packed, int nwords) {
    int w = blockIdx.x * blockDim.x + threadIdx.x;
    if (w >= nwords) return;
    const int4* p4 = (const int4*)(sp + (w << 4));
    int4 a = p4[0], b = p4[1], c = p4[2], d = p4[3];
    unsigned v =
        (unsigned)(a.x & 3)        | ((unsigned)(a.y & 3) << 2)  |
        ((unsigned)(a.z & 3) << 4) | ((unsigned)(a.w & 3) << 6)  |
        ((unsigned)(b.x & 3) << 8) | ((unsigned)(b.y & 3) << 10) |
        ((unsigned)(b.z & 3) << 12)| ((unsigned)(b.w & 3) << 14) |
        ((unsigned)(c.x & 3) << 16)| ((unsigned)(c.y & 3) << 18) |
        ((unsigned)(c.z & 3) << 20)| ((unsigned)(c.w & 3) << 22) |
        ((unsigned)(d.x & 3) << 24)| ((unsigned)(d.y & 3) << 26) |
        ((unsigned)(d.z & 3) << 28)| ((unsigned)(d.w & 3) << 30);
    packed[w] = v;
}

// ---------------------------------------------------------------------------
// init: species passthrough to out[0:n_species); zero the u64 accumulator.
__global__ void init_kernel(const int* __restrict__ species,
                            float* __restrict__ out,
                            unsigned long long* __restrict__ acc,
                            int n_species, int n_mol) {
    int i = blockIdx.x * blockDim.x + threadIdx.x;
    if (i < n_species) out[i] = (float)species[i];
    if (i < n_mol)     acc[i] = 0ull;
}

// ---------------------------------------------------------------------------
// Fused main kernel. LDS: 64KB packed species + 16KB u32 bins + 4x tab copies.
__global__ __launch_bounds__(NT, 1)
void srb_fused_u32(const unsigned* __restrict__ packed_ws,
                   const int* __restrict__ ai,     // [2, P]
                   const float* __restrict__ dist, // [P] angstrom
                   const float* __restrict__ pre_tab,   // 16 floats (negative)
                   const float* __restrict__ dfac_tab,  // 16 floats
                   unsigned long long* __restrict__ acc, // [n_mol]
                   int P, int mol_shift) {
    __shared__ unsigned packed[16384]; // 64KB: 2-bit species, all atoms
    __shared__ unsigned binsu[4096];   // 16KB: fixed-point per-mol sums
    __shared__ float2 tabr[4][18];     // 4 padded copies: (|pre|, dfac)

    const int t = threadIdx.x;
    for (int i = t; i < 4096; i += NT) binsu[i] = 0u;
    if (t < 64) {
        int e = t & 15;
        tabr[t >> 4][e] = make_float2(-pre_tab[e], dfac_tab[e]); // magnitude
    }
    {
        int4* dst = (int4*)packed;
        const int4* src = (const int4*)packed_ws;
        for (int i = t; i < 4096; i += NT) dst[i] = src[i];
    }
    __syncthreads();

    const float a2b   = (float)1.8897261258369282;
    const float rc    = (float)(5.2 * 1.8897261258369282);
    const float rcinv = (float)(1.0 / (5.2 * 1.8897261258369282));
    const int   copy  = t & 3;

    auto body = [&](int a0, int a1, float dang) {
        unsigned ua0 = (unsigned)a0, ua1 = (unsigned)a1;
        unsigned s0 = (packed[ua0 >> 4] >> ((ua0 & 15u) << 1)) & 3u;
        unsigned s1 = (packed[ua1 >> 4] >> ((ua1 & 15u) << 1)) & 3u;
        float2 td = tabr[copy][(s0 << 2) | s1];
        float db = dang * a2b;
        float x  = db * rcinv;
        float arg = td.y * db + (1.0f - 1.0f / (1.0f - x * x));
        float mag = td.x * __expf(arg);     // td.x = |pre| > 0
        mag = (db < rc) ? mag : 0.0f;       // exact 0 beyond cutoff
        unsigned q = (unsigned)(mag * SCALE_F); // trunc; < 2^21 always
        if (q) atomicAdd(&binsu[ua0 >> mol_shift], q); // native ds_add_u32
    };

    const int nv     = P >> 2;
    const int stride = (int)gridDim.x * NT;
    const int4*   v0 = (const int4*)ai;
    const int4*   v1 = (const int4*)(ai + P);
    const float4* dv = (const float4*)dist;
    for (int v = (int)blockIdx.x * NT + t; v < nv; v += stride) {
        int4 i0 = v0[v]; int4 i1 = v1[v]; float4 dd = dv[v];
        body(i0.x, i1.x, dd.x); body(i0.y, i1.y, dd.y);
        body(i0.z, i1.z, dd.z); body(i0.w, i1.w, dd.w);
    }

    __syncthreads();
    for (int i = t; i < 4096; i += NT) {
        unsigned v = binsu[i];
        if (v) atomicAdd(&acc[i], (unsigned long long)v); // native u64 atomic
    }
}

// ---------------------------------------------------------------------------
// final: out_e[m] = energies[m] - acc[m] * 2^-27  (exact in double)
__global__ void final_kernel(const unsigned long long* __restrict__ acc,
                             const float* __restrict__ energies,
                             float* __restrict__ out_e, int n_mol) {
    int m = blockIdx.x * blockDim.x + threadIdx.x;
    if (m < n_mol)
        out_e[m] = energies[m] - (float)((double)acc[m] * INV_SCALE);
}

// ---------------------------------------------------------------------------
// Fallback main kernel (P not multiple of 4): scalar loop, same math.
__global__ __launch_bounds__(NT, 1)
void srb_fused_scalar(const unsigned* __restrict__ packed_ws,
                      const int* __restrict__ ai,
                      const float* __restrict__ dist,
                      const float* __restrict__ pre_tab,
                      const float* __restrict__ dfac_tab,
                      unsigned long long* __restrict__ acc,
                      int P, int mol_shift) {
    __shared__ unsigned packed[16384];
    __shared__ unsigned binsu[4096];
    __shared__ float2 tabr[4][18];
    const int t = threadIdx.x;
    for (int i = t; i < 4096; i += NT) binsu[i] = 0u;
    if (t < 64) {
        int e = t & 15;
        tabr[t >> 4][e] = make_float2(-pre_tab[e], dfac_tab[e]);
    }
    {
        int4* dst = (int4*)packed;
        const int4* src = (const int4*)packed_ws;
        for (int i = t; i < 4096; i += NT) dst[i] = src[i];
    }
    __syncthreads();
    const float a2b   = (float)1.8897261258369282;
    const float rc    = (float)(5.2 * 1.8897261258369282);
    const float rcinv = (float)(1.0 / (5.2 * 1.8897261258369282));
    const int   copy  = t & 3;
    const int stride = (int)gridDim.x * NT;
    for (int p = (int)blockIdx.x * NT + t; p < P; p += stride) {
        unsigned ua0 = (unsigned)ai[p], ua1 = (unsigned)ai[P + p];
        unsigned s0 = (packed[ua0 >> 4] >> ((ua0 & 15u) << 1)) & 3u;
        unsigned s1 = (packed[ua1 >> 4] >> ((ua1 & 15u) << 1)) & 3u;
        float2 td = tabr[copy][(s0 << 2) | s1];
        float db = dist[p] * a2b;
        float x  = db * rcinv;
        float arg = td.y * db + (1.0f - 1.0f / (1.0f - x * x));
        float mag = td.x * __expf(arg);
        mag = (db < rc) ? mag : 0.0f;
        unsigned q = (unsigned)(mag * SCALE_F);
        if (q) atomicAdd(&binsu[ua0 >> mol_shift], q);
    }
    __syncthreads();
    for (int i = t; i < 4096; i += NT) {
        unsigned v = binsu[i];
        if (v) atomicAdd(&acc[i], (unsigned long long)v);
    }
}

// ---------------------------------------------------------------------------
extern "C" void kernel_launch(void* const* d_in, const int* in_sizes, int n_in,
                              void* d_out, int out_size, void* d_ws, size_t ws_size,
                              hipStream_t stream) {
    const int*   species  = (const int*)d_in[0];
    const float* energies = (const float*)d_in[1];
    const int*   ai       = (const int*)d_in[2];
    const float* dist     = (const float*)d_in[3];
    const float* pre_tab  = (const float*)d_in[4];
    const float* dfac_tab = (const float*)d_in[5];

    const int n_species = in_sizes[0];            // 262144
    const int n_mol     = in_sizes[1];            // 4096
    const int P         = in_sizes[3];            // 16777216
    const int n_atoms   = n_species / n_mol;      // 64

    int mol_shift = 0;
    while ((1 << mol_shift) < n_atoms) ++mol_shift; // 6

    float* out   = (float*)d_out;
    float* out_e = out + n_species;

    const int    nwords    = n_species / 16;              // 16384
    const size_t packed_sz = (size_t)nwords * 4;          // 64KB

    unsigned*           packed = (unsigned*)d_ws;
    unsigned long long* acc    = (unsigned long long*)((char*)d_ws + packed_sz);

    init_kernel<<<(n_species + 255) / 256, 256, 0, stream>>>(
        species, out, acc, n_species, n_mol);
    pack_species_kernel<<<(nwords + 255) / 256, 256, 0, stream>>>(
        species, packed, nwords);

    if ((P & 3) == 0) {
        srb_fused_u32<<<NBLK, NT, 0, stream>>>(
            packed, ai, dist, pre_tab, dfac_tab, acc, P, mol_shift);
    } else {
        srb_fused_scalar<<<NBLK, NT, 0, stream>>>(
            packed, ai, dist, pre_tab, dfac_tab, acc, P, mol_shift);
    }
    final_kernel<<<(n_mol + 255) / 256, 256, 0, stream>>>(
        acc, energies, out_e, n_mol);
}